// Round 7
// baseline (310.678 us; speedup 1.0000x reference)
//
#include <hip/hip_runtime.h>
#include <hip/hip_bf16.h>
#include <stdint.h>

// LinearTimeSelfAttention MI355X, round 11:
//  - 2 compute dispatches: memset(ctxP+cnt) -> k1f -> k3.
//    k2bc absorbed into k1f as a LAST-ARRIVER tail:
//      * every block: fence-free memory-side atomicAdd into 8 ctx replicas
//        (R1/R4-proven), then raw `s_waitcnt vmcnt(0)` (queue drain, NOT a
//        cache fence -- R3 proved fences catastrophic), then one memory-side
//        counter bump;
//      * 512th arriver alone reduces the replicas via relaxed agent-scope
//        loads (R6-proven coherent with memory-side atomics) and computes
//        Bm/cvec (fp32, chunked o x 32 in LDS), plain stores -- visible to
//        k3 across the dispatch boundary.
//  - R6 lesson recorded: cg::grid().sync() ~65us each @512 blocks (L2-inv
//    fences; FETCH doubled) -> cooperative fusion abandoned.
// Folding: y = Bm@x + cvec; Bm = A@W_q; A = (W_out ctx)/S;
// ctx = sum_n e^k v^T; S = sum_n e^k.

#define NPOS 147456      // 384*384
#define NTILES 2304      // NPOS / 64
#define NB1 512          // 2 blocks/CU exactly

typedef __attribute__((ext_vector_type(8))) short short8;
typedef __attribute__((ext_vector_type(4))) float floatx4;

__device__ __forceinline__ uint16_t f2bf(float f) {
    uint32_t u = __float_as_uint(f);
    return (uint16_t)((u + 0x7fffu + ((u >> 16) & 1u)) >> 16);   // RNE
}
__device__ __forceinline__ uint32_t pack2(float a, float b) {
#if __has_builtin(__builtin_amdgcn_cvt_pk_bf16_f32)
    auto r = __builtin_amdgcn_cvt_pk_bf16_f32(a, b);
    uint32_t u; __builtin_memcpy(&u, &r, sizeof(u));
    return u;
#else
    return (uint32_t)f2bf(a) | ((uint32_t)f2bf(b) << 16);
#endif
}
// relaxed agent-scope load: bypasses the (non-coherent) per-XCD L2,
// coherent with memory-side atomicAdd. No fence. [R6-proven]
__device__ __forceinline__ float aloadf(const float* p) {
    return __hip_atomic_load(p, __ATOMIC_RELAXED, __HIP_MEMORY_SCOPE_AGENT);
}

// strides in 32-bit LDS words
#define XS_STRIDE 68     // 136 bf16 per n-row (128 ch + 8 pad)
#define PS_STRIDE 36     // 72 bf16 per kvrow (64 n + 8 pad)
#define WST_STRIDE 132   // W staging: 128 f32 + 4 pad

// ---- helpers ----
__device__ __forceinline__ void k1_load(const float* __restrict__ xb, float* pf) {
    #pragma unroll
    for (int i = 0; i < 32; ++i) pf[i] = xb[(size_t)i * NPOS];
}
__device__ __forceinline__ void k1_store(uint32_t* Xsbuf, const float* pf, int lane, int c0) {
    #pragma unroll
    for (int i = 0; i < 8; ++i) {
        uint2 w;
        w.x = pack2(pf[i * 4 + 0], pf[i * 4 + 1]);
        w.y = pack2(pf[i * 4 + 2], pf[i * 4 + 3]);
        *(uint2*)&Xsbuf[lane * XS_STRIDE + (c0 + i * 4) / 2] = w;
    }
}
__device__ __forceinline__ void k1_tile(
    const uint32_t* __restrict__ Xsbuf, uint32_t* __restrict__ Psw,
    const short8 (&wfr)[4][4], const float (&biasv)[4],
    floatx4 (&acc2)[4], float (&sacc)[2], int m, int quad)
{
    #pragma unroll
    for (int nt = 0; nt < 4; ++nt) {
        short8 afr[4];
        #pragma unroll
        for (int ks = 0; ks < 4; ++ks)
            afr[ks] = *(const short8*)&Xsbuf[(nt * 16 + m) * XS_STRIDE + ks * 16 + quad * 4];
        floatx4 pa[4];
        #pragma unroll
        for (int kt = 0; kt < 4; ++kt) pa[kt] = (floatx4){0.f, 0.f, 0.f, 0.f};
        #pragma unroll
        for (int ks = 0; ks < 4; ++ks)
            #pragma unroll
            for (int kt = 0; kt < 4; ++kt)
                pa[kt] = __builtin_amdgcn_mfma_f32_16x16x32_bf16(afr[ks], wfr[kt][ks], pa[kt], 0, 0, 0);
        #pragma unroll
        for (int kt = 0; kt < 4; ++kt) {
            float v0 = pa[kt][0] + biasv[kt];
            float v1 = pa[kt][1] + biasv[kt];
            float v2 = pa[kt][2] + biasv[kt];
            float v3 = pa[kt][3] + biasv[kt];
            if (kt < 2) {   // k rows of this head
                v0 = __expf(v0); v1 = __expf(v1);
                v2 = __expf(v2); v3 = __expf(v3);
                sacc[kt] += (v0 + v1) + (v2 + v3);
            }
            uint2 w;
            w.x = pack2(v0, v1);
            w.y = pack2(v2, v3);
            *(uint2*)&Psw[(kt * 16 + m) * PS_STRIDE + nt * 8 + quad * 2] = w;
        }
    }
    #pragma unroll
    for (int ks = 0; ks < 2; ++ks) {
        short8 ea[2], vb[2];
        #pragma unroll
        for (int dt = 0; dt < 2; ++dt)
            ea[dt] = *(const short8*)&Psw[(dt * 16 + m) * PS_STRIDE + ks * 16 + quad * 4];
        #pragma unroll
        for (int et = 0; et < 2; ++et)
            vb[et] = *(const short8*)&Psw[(32 + et * 16 + m) * PS_STRIDE + ks * 16 + quad * 4];
        #pragma unroll
        for (int dt = 0; dt < 2; ++dt)
            #pragma unroll
            for (int et = 0; et < 2; ++et)
                acc2[dt * 2 + et] = __builtin_amdgcn_mfma_f32_16x16x32_bf16(ea[dt], vb[et], acc2[dt * 2 + et], 0, 0, 0);
    }
}

// ---------------- K1f: phase1 + atomic reduce + last-arriver Bm tail --------
__global__ __launch_bounds__(256, 2) void k1f(
    const float* __restrict__ x, const float* __restrict__ w_qkv,
    const float* __restrict__ b_qkv, const float* __restrict__ w_out,
    const float* __restrict__ b_out, float* __restrict__ ctxP,
    int* __restrict__ cnt, uint32_t* __restrict__ Bmb,
    float* __restrict__ cvec, int nb1)
{
    __shared__ uint32_t smem[2 * 64 * XS_STRIDE + 256 * PS_STRIDE];   // 71680 B
    __shared__ int lastFlag;

    const int t = threadIdx.x;
    const int lane = t & 63;
    const int wavu = __builtin_amdgcn_readfirstlane(t >> 6);
    const int m = lane & 15, quad = lane >> 4;
    const int c0 = wavu * 32;
    const int b = blockIdx.x;

    // ---- phase 1 (R4-proven) ----
    {
        uint32_t* const Xs0 = smem;
        uint32_t* const Xs1 = smem + 64 * XS_STRIDE;
        uint32_t* const Ps  = smem + 2 * 64 * XS_STRIDE;
        uint32_t* const Psw = &Ps[wavu * 64 * PS_STRIDE];

        const int T0 = NTILES / nb1, R = NTILES % nb1;
        const int cnt_tiles = T0 + (b < R ? 1 : 0);
        const int s0 = (b < R) ? b * (T0 + 1) : R * (T0 + 1) + (b - R) * T0;

        const float* xw = x + (size_t)c0 * NPOS + lane;
        float pfA[32], pfB[32];

        k1_load(xw + (size_t)s0 * 64, pfA);

        // W fragments via LDS staging, coalesced 256B reads
        short8 wfr[4][4];
        float biasv[4];
        float* const Wst = (float*)smem + wavu * (32 * WST_STRIDE);
        #pragma unroll
        for (int pass = 0; pass < 2; ++pass) {
            const int rbase = (pass == 0 ? 128 : 256) + wavu * 32;
            const float* g = w_qkv + (size_t)rbase * 128;
            #pragma unroll
            for (int i = 0; i < 64; ++i) {
                const int idx = i * 64 + lane;
                Wst[(idx >> 7) * WST_STRIDE + (idx & 127)] = g[idx];
            }
            __syncthreads();
            #pragma unroll
            for (int kt = 0; kt < 2; ++kt) {
                const int lr = kt * 16 + m;
                #pragma unroll
                for (int ks = 0; ks < 4; ++ks) {
                    const float* p = &Wst[lr * WST_STRIDE + ks * 32 + quad * 8];
                    float4 a = *(const float4*)p;
                    float4 c = *(const float4*)(p + 4);
                    short8 w;
                    w[0] = (short)f2bf(a.x); w[1] = (short)f2bf(a.y);
                    w[2] = (short)f2bf(a.z); w[3] = (short)f2bf(a.w);
                    w[4] = (short)f2bf(c.x); w[5] = (short)f2bf(c.y);
                    w[6] = (short)f2bf(c.z); w[7] = (short)f2bf(c.w);
                    wfr[pass * 2 + kt][ks] = w;
                }
                biasv[pass * 2 + kt] = b_qkv[rbase + kt * 16 + m];
            }
            __syncthreads();
        }

        floatx4 acc2[4];
        #pragma unroll
        for (int i = 0; i < 4; ++i) acc2[i] = (floatx4){0.f, 0.f, 0.f, 0.f};
        float sacc[2] = {0.f, 0.f};

        if (cnt_tiles > 1) k1_load(xw + (size_t)(s0 + 1) * 64, pfB);
        k1_store(Xs0, pfA, lane, c0);
        __syncthreads();

        for (int i = 0; i < cnt_tiles; i += 2) {
            if (i + 2 < cnt_tiles) k1_load(xw + (size_t)(s0 + i + 2) * 64, pfA);
            k1_tile(Xs0, Psw, wfr, biasv, acc2, sacc, m, quad);
            if (i + 1 < cnt_tiles) k1_store(Xs1, pfB, lane, c0);
            __syncthreads();
            if (i + 1 < cnt_tiles) {
                if (i + 3 < cnt_tiles) k1_load(xw + (size_t)(s0 + i + 3) * 64, pfB);
                k1_tile(Xs1, Psw, wfr, biasv, acc2, sacc, m, quad);
                if (i + 2 < cnt_tiles) k1_store(Xs0, pfA, lane, c0);
                __syncthreads();
            }
        }

        // fence-free memory-side atomic reduce into replica (b & 7)
        float* __restrict__ dst = ctxP + (size_t)(b & 7) * 4224;
        #pragma unroll
        for (int dt = 0; dt < 2; ++dt)
            #pragma unroll
            for (int et = 0; et < 2; ++et)
                #pragma unroll
                for (int r = 0; r < 4; ++r) {
                    const int d = dt * 16 + quad * 4 + r, e = et * 16 + m;
                    atomicAdd(&dst[wavu * 1024 + d * 32 + e], acc2[dt * 2 + et][r]);
                }
        #pragma unroll
        for (int kt = 0; kt < 2; ++kt) {
            float s = sacc[kt];
            s += __shfl_down(s, 32, 64);
            s += __shfl_down(s, 16, 64);
            if (lane < 16) atomicAdd(&dst[4096 + wavu * 32 + kt * 16 + lane], s);
        }
    }

    // ---- arrival: drain this wave's outstanding memory ops (NOT a cache
    // fence), then one memory-side counter RMW per block ----
    asm volatile("s_waitcnt vmcnt(0)" ::: "memory");
    __syncthreads();
    if (t == 0) {
        const int old = atomicAdd(cnt, 1);
        lastFlag = (old == nb1 - 1);
    }
    __syncthreads();
    if (!lastFlag) return;

    // ---- last-arriver tail: reduce replicas + Bm/cvec (fp32, == k2bc math) --
    float* const ctx33 = (float*)smem;            // 128*33 = 4224
    float* const Ssl   = ctx33 + 4224;            // 128
    float* const invS  = Ssl + 128;               // 128
    float* const A32   = invS + 128;              // 32*129 = 4128 (padded)
    for (int j = t; j < 4224; j += 256) {
        float s = 0.f;
        #pragma unroll
        for (int p = 0; p < 8; ++p) s += aloadf(&ctxP[p * 4224 + j]);
        if (j < 4096) ctx33[(j >> 5) * 33 + (j & 31)] = s;
        else          Ssl[j - 4096] = s;
    }
    __syncthreads();
    if (t < 128) invS[t] = 1.0f / Ssl[t];
    __syncthreads();

    const int hd = t & 127, oh = t >> 7;          // oh in {0,1}
    for (int oc = 0; oc < 4; ++oc) {              // 32 o-rows per chunk
        const int ob = oc * 32;
        // A32[oi][hd] = (w_out[o] . ctx[hd]) / S[hd]
        {
            const int h = hd >> 5;
            for (int oi = oh; oi < 32; oi += 2) {
                const int o = ob + oi;
                float s = 0.f;
                #pragma unroll
                for (int e = 0; e < 32; ++e)
                    s = fmaf(w_out[o * 128 + h * 32 + e], ctx33[hd * 33 + e], s);
                A32[oi * 129 + hd] = s * invS[hd];
            }
        }
        __syncthreads();
        // Bm rows (bf16-packed) for these o's
        {
            const int c = hd;
            for (int oi = oh; oi < 32; oi += 2) {
                const int o = ob + oi;
                float s = 0.f;
                #pragma unroll 16
                for (int k = 0; k < 128; ++k)
                    s = fmaf(A32[oi * 129 + k], w_qkv[k * 128 + c], s);
                const float shi = __shfl_down(s, 1, 64);
                if ((t & 1) == 0) Bmb[o * 64 + (c >> 1)] = pack2(s, shi);
            }
        }
        // cvec for these o's
        if (t < 32) {
            const int o = ob + t;
            float cs = b_out[o];
            #pragma unroll 16
            for (int k = 0; k < 128; ++k)
                cs = fmaf(A32[t * 129 + k], b_qkv[k], cs);
            cvec[o] = cs;
        }
        __syncthreads();
    }
}

// ---------------- K3: y = Bm @ x + cvec ----------------
__global__ __launch_bounds__(256) void k3(
    const float* __restrict__ x, const uint32_t* __restrict__ Bmb,
    const float* __restrict__ cvec, float* __restrict__ y)
{
    __shared__ uint32_t Xs[64 * XS_STRIDE];
    const int t = threadIdx.x, lane = t & 63;
    const int wavu = __builtin_amdgcn_readfirstlane(t >> 6);
    const int m = lane & 15, quad = lane >> 4;
    const int n0 = blockIdx.x * 64;
    const int c0 = wavu * 32;

    float pf[32];
    k1_load(x + (size_t)c0 * NPOS + n0 + lane, pf);

    short8 bfr[2][4];
    float cv[2];
    #pragma unroll
    for (int ot = 0; ot < 2; ++ot) {
        const int o = (wavu * 2 + ot) * 16 + m;
        cv[ot] = cvec[o];
        #pragma unroll
        for (int ks = 0; ks < 4; ++ks)
            bfr[ot][ks] = *(const short8*)&Bmb[o * 64 + ks * 16 + quad * 4];
    }
    k1_store(Xs, pf, lane, c0);
    __syncthreads();

    floatx4 acc[2][4];
    #pragma unroll
    for (int ot = 0; ot < 2; ++ot)
        #pragma unroll
        for (int nt = 0; nt < 4; ++nt) acc[ot][nt] = (floatx4){0.f, 0.f, 0.f, 0.f};
    #pragma unroll
    for (int nt = 0; nt < 4; ++nt) {
        short8 afr[4];
        #pragma unroll
        for (int ks = 0; ks < 4; ++ks)
            afr[ks] = *(const short8*)&Xs[(nt * 16 + m) * XS_STRIDE + ks * 16 + quad * 4];
        #pragma unroll
        for (int ks = 0; ks < 4; ++ks)
            #pragma unroll
            for (int ot = 0; ot < 2; ++ot)
                acc[ot][nt] = __builtin_amdgcn_mfma_f32_16x16x32_bf16(afr[ks], bfr[ot][ks], acc[ot][nt], 0, 0, 0);
    }
    #pragma unroll
    for (int ot = 0; ot < 2; ++ot) {
        const int o = (wavu * 2 + ot) * 16 + m;
        #pragma unroll
        for (int nt = 0; nt < 4; ++nt) {
            floatx4 v = acc[ot][nt];
            v.x += cv[ot]; v.y += cv[ot]; v.z += cv[ot]; v.w += cv[ot];
            *(floatx4*)(y + (size_t)o * NPOS + n0 + nt * 16 + quad * 4) = v;
        }
    }
}

extern "C" void kernel_launch(void* const* d_in, const int* in_sizes, int n_in,
                              void* d_out, int out_size, void* d_ws, size_t ws_size,
                              hipStream_t stream)
{
    const float* x     = (const float*)d_in[0];
    const float* w_qkv = (const float*)d_in[1];
    const float* b_qkv = (const float*)d_in[2];
    const float* w_out = (const float*)d_in[3];
    const float* b_out = (const float*)d_in[4];
    float* y = (float*)d_out;

    // ws: ctxP[8][4224] | cnt[4 int] | Bmb[8192 u32] | cvec[128]  (~169 KB)
    char* wsb = (char*)d_ws;
    float* ctxP   = (float*)wsb;
    int* cnt      = (int*)(ctxP + 8 * 4224);
    uint32_t* Bmb = (uint32_t*)(cnt + 4);
    float* cvec   = (float*)(Bmb + 8192);

    // one memset covers replicas + arrival counter
    hipMemsetAsync(ctxP, 0, (size_t)8 * 4224 * 4 + 16, stream);
    hipLaunchKernelGGL(k1f, dim3(NB1), dim3(256), 0, stream,
                       x, w_qkv, b_qkv, w_out, b_out, ctxP, cnt, Bmb, cvec, NB1);
    hipLaunchKernelGGL(k3, dim3(NTILES), dim3(256), 0, stream, x, Bmb, cvec, y);
}